// Round 6
// baseline (2532.820 us; speedup 1.0000x reference)
//
#include <hip/hip_runtime.h>
#include <hip/hip_bf16.h>
#include <math.h>

// NeuralCDE fused kernel, round 6: barrier-free register-chained MLP.
// 256 blocks x 256 threads (4 waves, 1/SIMD). Each WAVE independently owns 4
// batch rows and computes all 128 channels (M=128: 8 m-tiles; N=4 of 16 MFMA
// cols, cols 4-15 are harmless row-duplicates). A hidden-channel permutation
// h(ks,q,i) baked into the weight fragments makes layer l's D-fragment
// (bias-init + activation + cvt_pk) bit-exactly layer l+1's B-operand in the
// SAME registers -> zero LDS / zero barriers between layers. Per RK4 stage,
// one same-wave LDS round-trip redistributes k (D-layout, 16 lanes) to a
// distributed layout (8 f32/lane, all 64 lanes) for cheap state math.
// No s_barrier in the main loop at all; waves are fully independent.

typedef short bf16x8 __attribute__((ext_vector_type(8)));
typedef float f32x4  __attribute__((ext_vector_type(4)));
typedef float f32x2  __attribute__((ext_vector_type(2)));
typedef unsigned int u32x2 __attribute__((ext_vector_type(2)));
typedef unsigned int u32x4 __attribute__((ext_vector_type(4)));

#define MFMA16(a, b, c) __builtin_amdgcn_mfma_f32_16x16x32_bf16((a), (b), (c), 0, 0, 0)

__device__ __forceinline__ unsigned short f2bf(float x) {  // weight prep only
  unsigned int u = __float_as_uint(x);
  u += 0x7FFFu + ((u >> 16) & 1u);
  return (unsigned short)(u >> 16);
}

__device__ __forceinline__ unsigned int cvt_pk(float lo, float hi) {
  unsigned int r;  // D[15:0]=bf16(lo), D[31:16]=bf16(hi), RNE
  asm("v_cvt_pk_bf16_f32 %0, %1, %2" : "=v"(r) : "v"(lo), "v"(hi));
  return r;
}

// same-wave LDS ordering fence: all prior DS ops complete before any later
// DS op issues (cross-LANE exchange within one wave; no s_barrier needed).
__device__ __forceinline__ void lgkm0_fence() {
  asm volatile("s_waitcnt lgkmcnt(0)" ::: "memory");
  __builtin_amdgcn_sched_barrier(0);
}

__global__ __launch_bounds__(256, 1) void cde_fused(
    const float* __restrict__ z0, const float* __restrict__ coeffs,
    const float* __restrict__ W1, const float* __restrict__ b1,
    const float* __restrict__ W2, const float* __restrict__ b2,
    const float* __restrict__ W3, const float* __restrict__ b3,
    const float* __restrict__ Wr, const float* __restrict__ br,
    float* __restrict__ out) {
  // per-wave region (4224 B): zx [4 rows][136 ch] bf16 (272 B stride) @ +0,
  // kx [4 rows][784 B skewed f32] @ +1088.  biasD f32[3][128] shared at end.
  __shared__ __align__(16) char lds_all[4 * 4224 + 1536];

  const int tid  = (int)threadIdx.x;
  const int lane = tid & 63;
  const int wv   = tid >> 6;       // wave 0..3
  const int l15  = lane & 15;
  const int q    = lane >> 4;      // 0..3
  const int rl   = lane & 3;       // distributed: local row
  const int oct  = lane >> 2;      // distributed: channel octet 0..15
  const int row0 = (int)blockIdx.x * 16;
  const int grow = row0 + wv * 4 + rl;  // this lane's distributed global row

  char* const wb = lds_all + wv * 4224;   // zx base
  char* const kx = wb + 1088;             // kx base
  float* const biasD = (float*)(lds_all + 4 * 4224);

  // hoisted LDS addresses
  const int zrd  = (l15 & 3) * 272 + 8 * q;            // L1 B-frag read base
  const int zwr  = rl * 272 + oct * 16;                // distributed z/h write
  const int kxo  = 16 * q + 16 * (q >> 1);             // D-quad column skew
  const int kwrb = l15 * 784;                          // kx write row base (l15<4)
  const int krd  = rl * 784 + oct * 48;                // kx distributed read

  // ---------------- bias table (D-order read: plain f32[ch]) ----------------
  if (wv == 0) {
    for (int j = lane; j < 384; j += 64) {
      const float* bs = (j < 128) ? b1 : (j < 256 ? b2 : b3);
      biasD[j] = bs[j & 127];
    }
  }

  // ---------------- weight A-frags with h() rewiring (384 VGPR) -------------
  // frag(mt,ks) elem i holds W[h(ks,q,i)][16mt + l15]
  bf16x8 wfA[8][4], wfB[8][4], wfC[8][4];
  {
    auto build = [&](const float* Wsrc, bf16x8(&dst)[8][4]) {
#pragma unroll
      for (int mt = 0; mt < 8; ++mt)
#pragma unroll
        for (int ks = 0; ks < 4; ++ks) {
          bf16x8 f;
#pragma unroll
          for (int i = 0; i < 8; ++i) {
            const int j = 4 * ks + (i >> 1);
            const int h = 16 * (j >> 1) + 4 * q + 2 * (j & 1) + (i & 1);
            f[i] = (short)f2bf(Wsrc[h * 128 + 16 * mt + l15]);
          }
          dst[mt][ks] = f;
        }
    };
    build(W1, wfA);
    build(W2, wfB);
    build(W3, wfC);
  }

  // ---------------- state (distributed: 8 ch/lane, all 64 lanes) ------------
  float z[8];
  {
    const float* zp = z0 + (size_t)grow * 128 + oct * 8;
    const f32x4 a = *(const f32x4*)zp;
    const f32x4 b = *(const f32x4*)(zp + 4);
#pragma unroll
    for (int e = 0; e < 4; ++e) { z[e] = a[e]; z[4 + e] = b[e]; }
  }
  float c1v[8], c2b[8], c3b[8];  // c1, 2*c2, 3*c3 for current piece
  {
    const float* cb = coeffs + (size_t)grow * 64 * 512 + oct * 32;  // piece 0
#pragma unroll
    for (int jc = 0; jc < 8; ++jc) {
      const f32x2 c23 = *(const f32x2*)(cb + jc * 4 + 2);
      c1v[jc] = cb[jc * 4 + 1];
      c2b[jc] = 2.f * c23[0];
      c3b[jc] = 3.f * c23[1];
    }
  }
  {  // initial z -> zx (bf16, distributed write)
    u32x4 t;
#pragma unroll
    for (int k2 = 0; k2 < 4; ++k2) t[k2] = cvt_pk(z[2 * k2], z[2 * k2 + 1]);
    *(u32x4*)(wb + zwr) = t;
  }
  __syncthreads();  // biasD visibility (only barrier before readout)

  // ---------------- MLP: 3 layers fully in registers ----------------
  auto Lmm = [&](const bf16x8(&wf)[8][4], int bo, const bf16x8(&xk)[4],
                 f32x4(&acc)[8]) {
#pragma unroll
    for (int mt = 0; mt < 8; ++mt)
      acc[mt] = *(const f32x4*)(biasD + bo + 16 * mt + 4 * q);  // bias init
#pragma unroll
    for (int ks = 0; ks < 4; ++ks)
#pragma unroll
      for (int mt = 0; mt < 8; ++mt)
        acc[mt] = MFMA16(wf[mt][ks], xk[ks], acc[mt]);
  };

  auto run3 = [&](f32x4(&acc)[8]) {
    bf16x8 xk[4];
#pragma unroll
    for (int ks = 0; ks < 4; ++ks) {  // L1 input from zx (h-ordered b64 pair)
      const u32x2 lo = *(const u32x2*)(wb + zrd + ks * 64);
      const u32x2 hi = *(const u32x2*)(wb + zrd + ks * 64 + 32);
      u32x4 t; t[0] = lo[0]; t[1] = lo[1]; t[2] = hi[0]; t[3] = hi[1];
      xk[ks] = __builtin_bit_cast(bf16x8, t);
    }
    Lmm(wfA, 0, xk, acc);
    {  // ELU + pack: D-frag -> next B-operand (register identity)
      unsigned int d[16];
#pragma unroll
      for (int j = 0; j < 16; ++j) {
        float a = acc[j >> 1][2 * (j & 1)], b = acc[j >> 1][2 * (j & 1) + 1];
        a = fmaxf(a, __expf(fminf(a, 0.f)) - 1.f);
        b = fmaxf(b, __expf(fminf(b, 0.f)) - 1.f);
        d[j] = cvt_pk(a, b);
      }
#pragma unroll
      for (int ks = 0; ks < 4; ++ks) {
        u32x4 t; t[0]=d[4*ks]; t[1]=d[4*ks+1]; t[2]=d[4*ks+2]; t[3]=d[4*ks+3];
        xk[ks] = __builtin_bit_cast(bf16x8, t);
      }
    }
    Lmm(wfB, 128, xk, acc);
    {  // ReLU + pack
      unsigned int d[16];
#pragma unroll
      for (int j = 0; j < 16; ++j)
        d[j] = cvt_pk(fmaxf(acc[j >> 1][2 * (j & 1)], 0.f),
                      fmaxf(acc[j >> 1][2 * (j & 1) + 1], 0.f));
#pragma unroll
      for (int ks = 0; ks < 4; ++ks) {
        u32x4 t; t[0]=d[4*ks]; t[1]=d[4*ks+1]; t[2]=d[4*ks+2]; t[3]=d[4*ks+3];
        xk[ks] = __builtin_bit_cast(bf16x8, t);
      }
    }
    Lmm(wfC, 256, xk, acc);  // acc = k_pre (D layout, f32)
  };

  auto kx_trip = [&](const f32x4(&acc)[8], float(&kd)[8]) {
    if (l15 < 4) {
#pragma unroll
      for (int mt = 0; mt < 8; ++mt)
        *(f32x4*)(kx + kwrb + 96 * mt + kxo) = acc[mt];
    }
    lgkm0_fence();  // same-wave: writes visible to all lanes
    const f32x4 ka = *(const f32x4*)(kx + krd);
    const f32x4 kb = *(const f32x4*)(kx + krd + 16);
#pragma unroll
    for (int e = 0; e < 4; ++e) { kd[e] = ka[e]; kd[4 + e] = kb[e]; }
  };

  auto zx_write = [&](const float(&v)[8]) {
    u32x4 t;
#pragma unroll
    for (int k2 = 0; k2 < 4; ++k2) t[k2] = cvt_pk(v[2 * k2], v[2 * k2 + 1]);
    *(u32x4*)(wb + zwr) = t;
    lgkm0_fence();  // visible before next stage's zx reads
  };

  // ---------------- main loop: 64 pieces x 4 substeps ----------------
  float zacc[8];
#pragma unroll 1
  for (int p = 0; p < 64; ++p) {
#pragma unroll 1
    for (int sub = 0; sub < 4; ++sub) {
      const float s0 = 0.25f * (float)sub;
#pragma unroll
      for (int e = 0; e < 8; ++e) zacc[e] = z[e];

      // ---- stages 1..3 (k1,k2,k3) ----
#pragma unroll 1
      for (int st = 0; st < 3; ++st) {
        const float s  = s0 + (st ? 0.125f : 0.0f);
        const float ah = (st == 2) ? 0.25f : 0.125f;
        const float wz = (st == 0) ? (0.25f / 6.f) : (0.5f / 6.f);
        f32x4 acc[8];
        run3(acc);
        float kd[8];
        kx_trip(acc, kd);
        float h[8];
#pragma unroll
        for (int e = 0; e < 8; ++e) {
          const float dx = c1v[e] + (c2b[e] + c3b[e] * s) * s;
          const float k = kd[e] * dx;
          zacc[e] += wz * k;
          h[e] = z[e] + ah * k;
        }
        zx_write(h);
      }

      // ---- stage 4 (k4) + state update ----
      {
        f32x4 acc[8];
        run3(acc);
        float kd[8];
        kx_trip(acc, kd);
        float dxm[8];
        if (sub < 3) {
          const float sc = s0 + 0.25f;
#pragma unroll
          for (int e = 0; e < 8; ++e)
            dxm[e] = c1v[e] + (c2b[e] + c3b[e] * sc) * sc;
        } else if (p < 63) {
          // adopt next piece; dX(t+dt) = c1(next piece) at s=0
          const float* cb = coeffs + ((size_t)grow * 64 + (p + 1)) * 512 + oct * 32;
#pragma unroll
          for (int jc = 0; jc < 8; ++jc) {
            const f32x2 c23 = *(const f32x2*)(cb + jc * 4 + 2);
            const float c1n = cb[jc * 4 + 1];
            c1v[jc] = c1n;
            c2b[jc] = 2.f * c23[0];
            c3b[jc] = 3.f * c23[1];
            dxm[jc] = c1n;
          }
        } else {
          // u = 255: t+dt = 64 clips to piece 63 at s = 1
#pragma unroll
          for (int e = 0; e < 8; ++e) dxm[e] = c1v[e] + c2b[e] + c3b[e];
        }
        float zn[8];
#pragma unroll
        for (int e = 0; e < 8; ++e) {
          const float k = kd[e] * dxm[e];
          z[e] = zacc[e] + (0.25f / 6.f) * k;
          zn[e] = z[e];
        }
        zx_write(zn);
      }
    }
  }

  // ---------------- readout: out = zT @ Wr + br ----------------
  __syncthreads();  // all waves done; reuse LDS as fp32 zf[16][132]
  {
    float* zf = (float*)lds_all;
    *(f32x4*)(zf + (wv * 4 + rl) * 132 + oct * 8)     = f32x4{z[0], z[1], z[2], z[3]};
    *(f32x4*)(zf + (wv * 4 + rl) * 132 + oct * 8 + 4) = f32x4{z[4], z[5], z[6], z[7]};
  }
  __syncthreads();
  if (tid < 160) {
    const int row = tid / 10, o = tid - row * 10;
    const float* zf = (const float*)lds_all;
    float acc = br[o];
#pragma unroll 4
    for (int ch = 0; ch < 128; ++ch)
      acc = fmaf(zf[row * 132 + ch], Wr[ch * 10 + o], acc);
    out[(size_t)(row0 + row) * 10 + o] = acc;
  }
}

extern "C" void kernel_launch(void* const* d_in, const int* in_sizes, int n_in,
                              void* d_out, int out_size, void* d_ws, size_t ws_size,
                              hipStream_t stream) {
  const float* z0     = (const float*)d_in[0];
  const float* coeffs = (const float*)d_in[1];
  const float* W1 = (const float*)d_in[2]; const float* b1 = (const float*)d_in[3];
  const float* W2 = (const float*)d_in[4]; const float* b2 = (const float*)d_in[5];
  const float* W3 = (const float*)d_in[6]; const float* b3 = (const float*)d_in[7];
  const float* Wr = (const float*)d_in[8]; const float* br = (const float*)d_in[9];
  hipLaunchKernelGGL(cde_fused, dim3(256), dim3(256), 0, stream,
                     z0, coeffs, W1, b1, W2, b2, W3, b3, Wr, br, (float*)d_out);
}

// Round 8
// 933.758 us; speedup vs baseline: 2.7125x; 2.7125x over previous
//
#include <hip/hip_runtime.h>
#include <hip/hip_bf16.h>
#include <math.h>

// NeuralCDE fused kernel, round 7 (compile fix of round-7 submission).
// 256 blocks x 256 threads (4 waves); block owns 16 batch rows for all 256
// RK4 steps; wave w owns output channels [32w,32w+32). Operand-swapped MFMA
// (W^T = A in regs, X^T = B from LDS). NEW vs round 5:
//  - diagonal register identity: weights' K-dim is re-indexed by
//    k = 32ks + 16(i>>2) + 4q + (i&3), so a wave's D-frag (after act+cvt_pk)
//    IS its own-slice B-operand. The 2 own-slice MFMAs (+bias init) issue
//    BEFORE the barrier; only 3 ds_read_b128 remain after it; the exchange
//    write is a single ds_write_b128 of the packed B-frag words.
//  - depth-2 MFMA dependency chains (P: bias+own+ks1; Q: ks2+ks3; A=P+Q).
// z-space (z0/coeffs/b*/readout) stays un-permuted: L3's out-map is identity.

typedef short bf16x8 __attribute__((ext_vector_type(8)));
typedef float f32x4  __attribute__((ext_vector_type(4)));
typedef unsigned int u32x4 __attribute__((ext_vector_type(4)));

__device__ __forceinline__ f32x4 MFMA16(bf16x8 a, bf16x8 b, f32x4 c) {
  return __builtin_amdgcn_mfma_f32_16x16x32_bf16(a, b, c, 0, 0, 0);
}

__device__ __forceinline__ unsigned short f2bf(float x) {  // weight prep only
  unsigned int u = __float_as_uint(x);
  u += 0x7FFFu + ((u >> 16) & 1u);
  return (unsigned short)(u >> 16);
}

__device__ __forceinline__ unsigned int cvt_pk(float lo, float hi) {
  unsigned int r;  // D[15:0]=bf16(lo), D[31:16]=bf16(hi), RNE
  asm("v_cvt_pk_bf16_f32 %0, %1, %2" : "=v"(r) : "v"(lo), "v"(hi));
  return r;
}

// raw barrier: LDS-drain only (keeps global coeff prefetch loads in flight).
__device__ __forceinline__ void barrier_lgkm() {
  asm volatile("s_waitcnt lgkmcnt(0)" ::: "memory");
  __builtin_amdgcn_s_barrier();
  asm volatile("" ::: "memory");
}

__global__ __launch_bounds__(256, 1) void cde_fused(
    const float* __restrict__ z0, const float* __restrict__ coeffs,
    const float* __restrict__ W1, const float* __restrict__ b1,
    const float* __restrict__ W2, const float* __restrict__ b2,
    const float* __restrict__ W3, const float* __restrict__ b3,
    const float* __restrict__ Wr, const float* __restrict__ br,
    float* __restrict__ out) {
  // [2][16 rows][136 shorts]; row stride 272 B; slice ks at short-offset 32ks.
  __shared__ __align__(16) unsigned short zbuf[2][16][136];
  char* const lds = (char*)zbuf;

  const int tid  = (int)threadIdx.x;
  const int lane = tid & 63;
  const int wv   = tid >> 6;        // wave 0..3 (owns k-slice ks=wv)
  const int l15  = lane & 15;       // batch row within tile
  const int q    = lane >> 4;       // 0..3
  const int row0 = (int)blockIdx.x * 16;

  const f32x4 ZERO4 = {0.f, 0.f, 0.f, 0.f};

  // exchange addresses: slice ks lives at byte l15*272 + 64ks + 16q
  const int exb  = l15 * 272 + 16 * q;
  const int ownb = exb + 64 * wv;               // our b128 write
  const int ks1 = (wv + 1) & 3, ks2 = (wv + 2) & 3, ks3 = (wv + 3) & 3;
  const int off1 = exb + 64 * ks1, off2 = exb + 64 * ks2, off3 = exb + 64 * ks3;

  // ------------- weight A-frags, K-dim in B-identity order (96 VGPR) --------
  // frag(mt,ks) elem i holds W[32ks + 16*(i>>2) + 4q + (i&3)][32wv+16mt+l15]
  bf16x8 wf1[2][4], wf2[2][4], wf3[2][4];
#pragma unroll
  for (int mt = 0; mt < 2; ++mt) {
    const int col = 32 * wv + 16 * mt + l15;
#pragma unroll
    for (int ks = 0; ks < 4; ++ks) {
      bf16x8 fa, fb, fc;
#pragma unroll
      for (int i = 0; i < 8; ++i) {
        const int k = 32 * ks + 16 * (i >> 2) + 4 * q + (i & 3);
        fa[i] = (short)f2bf(W1[k * 128 + col]);
        fb[i] = (short)f2bf(W2[k * 128 + col]);
        fc[i] = (short)f2bf(W3[k * 128 + col]);
      }
      wf1[mt][ks] = fa; wf2[mt][ks] = fb; wf3[mt][ks] = fc;
    }
  }
  // biases (accumulator init): D elem r of tile mt = ch 32wv+16mt+4q+r
  f32x4 bv1[2], bv2[2], bv3[2];
#pragma unroll
  for (int mt = 0; mt < 2; ++mt) {
    bv1[mt] = *(const f32x4*)(b1 + 32 * wv + 16 * mt + 4 * q);
    bv2[mt] = *(const f32x4*)(b2 + 32 * wv + 16 * mt + 4 * q);
    bv3[mt] = *(const f32x4*)(b3 + 32 * wv + 16 * mt + 4 * q);
  }

  // ------------- coeff registers (e = mt*4+r -> row l15, ch 32wv+16mt+4q+r) --
  f32x4 cf[8];
  auto coeff_load = [&](int p) {
    const float* cb = coeffs + ((size_t)(row0 + l15) * 64 + p) * 512;
#pragma unroll
    for (int mt = 0; mt < 2; ++mt)
#pragma unroll
      for (int r = 0; r < 4; ++r)
        cf[mt * 4 + r] = *(const f32x4*)(cb + (32 * wv + 16 * mt + 4 * q + r) * 4);
  };
  float c1v[8], c2b[8], c3b[8];  // c1, 2*c2, 3*c3
  auto coeff_adopt = [&]() {
#pragma unroll
    for (int e = 0; e < 8; ++e) {
      c1v[e] = cf[e][1]; c2b[e] = 2.f * cf[e][2]; c3b[e] = 3.f * cf[e][3];
    }
  };

  // own B-frag registers (packed words, doubles as the LDS exchange payload)
  u32x4 zb;
  auto emit = [&](const float(&h)[8], int wbuf) {  // pack + keep + write b128
    u32x4 t;
    t[0] = cvt_pk(h[0], h[1]); t[1] = cvt_pk(h[2], h[3]);
    t[2] = cvt_pk(h[4], h[5]); t[3] = cvt_pk(h[6], h[7]);
    zb = t;
    *(u32x4*)(lds + wbuf * 4352 + ownb) = t;
  };

  // ------------- prologue -------------
  float zr[8];
  {
    const float* zp = z0 + (size_t)(row0 + l15) * 128 + 32 * wv + 4 * q;
    const f32x4 za = *(const f32x4*)zp;
    const f32x4 zc = *(const f32x4*)(zp + 16);
#pragma unroll
    for (int r = 0; r < 4; ++r) { zr[r] = za[r]; zr[4 + r] = zc[r]; }
  }
  coeff_load(0);
  coeff_adopt();
  {
    float h[8];
#pragma unroll
    for (int e = 0; e < 8; ++e) h[e] = zr[e];
    emit(h, 0);
  }

  float kx[8], sacc[8], dxb[8];

  // one layer: 2 own-slice MFMAs pre-barrier (from zb regs), 3 reads + 6
  // MFMAs post-barrier, two depth-2 chains per tile.
  auto layer = [&](const bf16x8(&wf)[2][4], const f32x4(&bv)[2], int rb,
                   f32x4& A0, f32x4& A1) {
    const bf16x8 xo = __builtin_bit_cast(bf16x8, zb);
    f32x4 P0 = MFMA16(wf[0][wv], xo, bv[0]);
    f32x4 P1 = MFMA16(wf[1][wv], xo, bv[1]);
    barrier_lgkm();
    const char* base = lds + rb * 4352;
    const bf16x8 x1 = *(const bf16x8*)(base + off1);
    const bf16x8 x2 = *(const bf16x8*)(base + off2);
    const bf16x8 x3 = *(const bf16x8*)(base + off3);
    P0 = MFMA16(wf[0][ks1], x1, P0);
    P1 = MFMA16(wf[1][ks1], x1, P1);
    f32x4 Q0 = MFMA16(wf[0][ks2], x2, ZERO4);
    f32x4 Q1 = MFMA16(wf[1][ks2], x2, ZERO4);
    Q0 = MFMA16(wf[0][ks3], x3, Q0);
    Q1 = MFMA16(wf[1][ks3], x3, Q1);
    A0 = P0 + Q0; A1 = P1 + Q1;
  };

  // one MLP eval; exchange buffers: L1 rd sp wr sp^1, L2 rd sp^1 wr sp,
  // L3 rd sp; result (incl. b3) -> kx
  auto run_f = [&](int sp) {
    f32x4 A0, A1;
    float h[8];
    layer(wf1, bv1, sp, A0, A1);
#pragma unroll
    for (int r = 0; r < 4; ++r) {  // ELU(v) = max(v, exp(min(v,0))-1)
      h[r]     = fmaxf(A0[r], __expf(fminf(A0[r], 0.f)) - 1.f);
      h[4 + r] = fmaxf(A1[r], __expf(fminf(A1[r], 0.f)) - 1.f);
    }
    emit(h, sp ^ 1);
    layer(wf2, bv2, sp ^ 1, A0, A1);
#pragma unroll
    for (int r = 0; r < 4; ++r) {
      h[r] = fmaxf(A0[r], 0.f); h[4 + r] = fmaxf(A1[r], 0.f);  // ReLU
    }
    emit(h, sp);
    layer(wf3, bv3, sp, A0, A1);
#pragma unroll
    for (int r = 0; r < 4; ++r) { kx[r] = A0[r]; kx[4 + r] = A1[r]; }
  };

  // ------------- main loop: 64 pieces x 4 unrolled substeps -------------
#pragma unroll 1
  for (int p = 0; p < 64; ++p) {
    const bool pre = p < 63;
    if (pre) coeff_load(p + 1);  // prefetch next piece into regs (vmem queue)

#pragma unroll
    for (int sub = 0; sub < 4; ++sub) {
      const float s0 = 0.25f * (float)sub;  // compile-time

      // ---- stage 1: k1 = f(z)*dX(s0); exchange base buf0 ----
      run_f(0);
      {
        float h[8];
#pragma unroll
        for (int e = 0; e < 8; ++e) {
          const float dx = c1v[e] + (c2b[e] + c3b[e] * s0) * s0;
          kx[e] *= dx; sacc[e] = kx[e];
          h[e] = zr[e] + 0.125f * kx[e];
        }
        emit(h, 1);
      }

      // ---- stage 2: k2 at s0+0.125; base buf1 ----
      run_f(1);
      {
        const float sb = s0 + 0.125f;
        float h[8];
#pragma unroll
        for (int e = 0; e < 8; ++e) {
          dxb[e] = c1v[e] + (c2b[e] + c3b[e] * sb) * sb;
          kx[e] *= dxb[e]; sacc[e] += 2.f * kx[e];
          h[e] = zr[e] + 0.125f * kx[e];
        }
        emit(h, 0);
      }

      // ---- stage 3: k3 at same s as k2 (dx reused); base buf0 ----
      run_f(0);
      {
        float h[8];
#pragma unroll
        for (int e = 0; e < 8; ++e) {
          kx[e] *= dxb[e]; sacc[e] += 2.f * kx[e];
          h[e] = zr[e] + 0.25f * kx[e];
        }
        emit(h, 1);
      }

      // ---- stage 4: k4 at t+dt; base buf1 ----
      run_f(1);
      if (sub == 3) {
        if (pre) {
#pragma unroll
          for (int e = 0; e < 8; ++e) kx[e] *= cf[e][1];  // next piece, s=0
        } else {
#pragma unroll
          for (int e = 0; e < 8; ++e) kx[e] *= (c1v[e] + c2b[e] + c3b[e]);  // s=1
        }
      } else {
        const float sc = s0 + 0.25f;
#pragma unroll
        for (int e = 0; e < 8; ++e)
          kx[e] *= c1v[e] + (c2b[e] + c3b[e] * sc) * sc;
      }
      {
        float h[8];
#pragma unroll
        for (int e = 0; e < 8; ++e) {
          sacc[e] += kx[e];
          zr[e] += (0.25f / 6.f) * sacc[e];
          h[e] = zr[e];
        }
        emit(h, 0);  // next step's f-input -> buf0
      }
    }
    if (pre) coeff_adopt();
  }

  // ------------- readout: out = zT @ Wr + br -------------
  __syncthreads();  // all exchange reads done; reuse LDS as fp32 zf[16][132]
  {
    float* zf = (float*)lds;
    *(f32x4*)(zf + l15 * 132 + 32 * wv + 4 * q)      = f32x4{zr[0], zr[1], zr[2], zr[3]};
    *(f32x4*)(zf + l15 * 132 + 32 * wv + 16 + 4 * q) = f32x4{zr[4], zr[5], zr[6], zr[7]};
  }
  __syncthreads();
  if (tid < 160) {
    const int row = tid / 10, o = tid - row * 10;
    const float* zf = (const float*)lds;
    float acc = br[o];
#pragma unroll 4
    for (int ch = 0; ch < 128; ++ch)
      acc = fmaf(zf[row * 132 + ch], Wr[ch * 10 + o], acc);
    out[(size_t)(row0 + row) * 10 + o] = acc;
  }
}

extern "C" void kernel_launch(void* const* d_in, const int* in_sizes, int n_in,
                              void* d_out, int out_size, void* d_ws, size_t ws_size,
                              hipStream_t stream) {
  const float* z0     = (const float*)d_in[0];
  const float* coeffs = (const float*)d_in[1];
  const float* W1 = (const float*)d_in[2]; const float* b1 = (const float*)d_in[3];
  const float* W2 = (const float*)d_in[4]; const float* b2 = (const float*)d_in[5];
  const float* W3 = (const float*)d_in[6]; const float* b3 = (const float*)d_in[7];
  const float* Wr = (const float*)d_in[8]; const float* br = (const float*)d_in[9];
  hipLaunchKernelGGL(cde_fused, dim3(256), dim3(256), 0, stream,
                     z0, coeffs, W1, b1, W2, b2, W3, b3, Wr, br, (float*)d_out);
}

// Round 9
// 881.458 us; speedup vs baseline: 2.8734x; 1.0593x over previous
//
#include <hip/hip_runtime.h>
#include <hip/hip_bf16.h>
#include <math.h>

// NeuralCDE fused kernel, round 9.
// 256 blocks x 256 threads (4 waves); block owns 16 batch rows for all 256
// RK4 steps; wave w owns output channels [32w,32w+32). Operand-swapped MFMA
// (W^T = A in regs, X^T = B from LDS) with the diagonal register identity
// (k = 32ks + 16(i>>2) + 4q + (i&3)): a wave's D-frag after act+cvt_pk IS its
// own-slice B-operand -> 2 own-slice MFMAs issue pre-barrier, 3 ds_read_b128
// post-barrier, exchange write is one ds_write_b128.
// vs round 8: single depth-4 MFMA chains (bias-init start, no P/Q split, no
// extra adds), and dx(stage4) is carried into the next stage-1 (dxm reuse).

typedef short bf16x8 __attribute__((ext_vector_type(8)));
typedef float f32x4  __attribute__((ext_vector_type(4)));
typedef unsigned int u32x4 __attribute__((ext_vector_type(4)));

__device__ __forceinline__ f32x4 MFMA16(bf16x8 a, bf16x8 b, f32x4 c) {
  return __builtin_amdgcn_mfma_f32_16x16x32_bf16(a, b, c, 0, 0, 0);
}

__device__ __forceinline__ unsigned short f2bf(float x) {  // weight prep only
  unsigned int u = __float_as_uint(x);
  u += 0x7FFFu + ((u >> 16) & 1u);
  return (unsigned short)(u >> 16);
}

__device__ __forceinline__ unsigned int cvt_pk(float lo, float hi) {
  unsigned int r;  // D[15:0]=bf16(lo), D[31:16]=bf16(hi), RNE
  asm("v_cvt_pk_bf16_f32 %0, %1, %2" : "=v"(r) : "v"(lo), "v"(hi));
  return r;
}

// raw barrier: LDS-drain only (keeps global coeff prefetch loads in flight).
__device__ __forceinline__ void barrier_lgkm() {
  asm volatile("s_waitcnt lgkmcnt(0)" ::: "memory");
  __builtin_amdgcn_s_barrier();
  asm volatile("" ::: "memory");
}

__global__ __launch_bounds__(256, 1) void cde_fused(
    const float* __restrict__ z0, const float* __restrict__ coeffs,
    const float* __restrict__ W1, const float* __restrict__ b1,
    const float* __restrict__ W2, const float* __restrict__ b2,
    const float* __restrict__ W3, const float* __restrict__ b3,
    const float* __restrict__ Wr, const float* __restrict__ br,
    float* __restrict__ out) {
  // [2][16 rows][136 shorts]; row stride 272 B; slice ks at byte-offset 64ks.
  __shared__ __align__(16) unsigned short zbuf[2][16][136];
  char* const lds = (char*)zbuf;

  const int tid  = (int)threadIdx.x;
  const int lane = tid & 63;
  const int wv   = tid >> 6;        // wave 0..3 (owns k-slice ks=wv)
  const int l15  = lane & 15;       // batch row within tile
  const int q    = lane >> 4;       // 0..3
  const int row0 = (int)blockIdx.x * 16;

  // exchange addresses: slice ks lives at byte l15*272 + 64ks + 16q
  const int exb  = l15 * 272 + 16 * q;
  const int ownb = exb + 64 * wv;               // our b128 write
  const int ks1 = (wv + 1) & 3, ks2 = (wv + 2) & 3, ks3 = (wv + 3) & 3;
  const int off1 = exb + 64 * ks1, off2 = exb + 64 * ks2, off3 = exb + 64 * ks3;

  // ------------- weight A-frags, K-dim in B-identity order (96 VGPR) --------
  // frag(mt,ks) elem i holds W[32ks + 16*(i>>2) + 4q + (i&3)][32wv+16mt+l15]
  bf16x8 wf1[2][4], wf2[2][4], wf3[2][4];
#pragma unroll
  for (int mt = 0; mt < 2; ++mt) {
    const int col = 32 * wv + 16 * mt + l15;
#pragma unroll
    for (int ks = 0; ks < 4; ++ks) {
      bf16x8 fa, fb, fc;
#pragma unroll
      for (int i = 0; i < 8; ++i) {
        const int k = 32 * ks + 16 * (i >> 2) + 4 * q + (i & 3);
        fa[i] = (short)f2bf(W1[k * 128 + col]);
        fb[i] = (short)f2bf(W2[k * 128 + col]);
        fc[i] = (short)f2bf(W3[k * 128 + col]);
      }
      wf1[mt][ks] = fa; wf2[mt][ks] = fb; wf3[mt][ks] = fc;
    }
  }
  // biases (accumulator init): D elem r of tile mt = ch 32wv+16mt+4q+r
  f32x4 bv1[2], bv2[2], bv3[2];
#pragma unroll
  for (int mt = 0; mt < 2; ++mt) {
    bv1[mt] = *(const f32x4*)(b1 + 32 * wv + 16 * mt + 4 * q);
    bv2[mt] = *(const f32x4*)(b2 + 32 * wv + 16 * mt + 4 * q);
    bv3[mt] = *(const f32x4*)(b3 + 32 * wv + 16 * mt + 4 * q);
  }

  // ------------- coeff registers (e = mt*4+r -> row l15, ch 32wv+16mt+4q+r) --
  f32x4 cf[8];
  auto coeff_load = [&](int p) {
    const float* cb = coeffs + ((size_t)(row0 + l15) * 64 + p) * 512;
#pragma unroll
    for (int mt = 0; mt < 2; ++mt)
#pragma unroll
      for (int r = 0; r < 4; ++r)
        cf[mt * 4 + r] = *(const f32x4*)(cb + (32 * wv + 16 * mt + 4 * q + r) * 4);
  };
  float c1v[8], c2b[8], c3b[8];  // c1, 2*c2, 3*c3
  auto coeff_adopt = [&]() {
#pragma unroll
    for (int e = 0; e < 8; ++e) {
      c1v[e] = cf[e][1]; c2b[e] = 2.f * cf[e][2]; c3b[e] = 3.f * cf[e][3];
    }
  };

  // own B-frag registers (packed words, doubles as the LDS exchange payload)
  u32x4 zb;
  auto emit = [&](const float(&h)[8], int wbuf) {  // pack + keep + write b128
    u32x4 t;
    t[0] = cvt_pk(h[0], h[1]); t[1] = cvt_pk(h[2], h[3]);
    t[2] = cvt_pk(h[4], h[5]); t[3] = cvt_pk(h[6], h[7]);
    zb = t;
    *(u32x4*)(lds + wbuf * 4352 + ownb) = t;
  };

  // ------------- prologue -------------
  float zr[8];
  {
    const float* zp = z0 + (size_t)(row0 + l15) * 128 + 32 * wv + 4 * q;
    const f32x4 za = *(const f32x4*)zp;
    const f32x4 zc = *(const f32x4*)(zp + 16);
#pragma unroll
    for (int r = 0; r < 4; ++r) { zr[r] = za[r]; zr[4 + r] = zc[r]; }
  }
  coeff_load(0);
  coeff_adopt();
  {
    float h[8];
#pragma unroll
    for (int e = 0; e < 8; ++e) h[e] = zr[e];
    emit(h, 0);
  }

  float kx[8], sacc[8], dxb[8], dxm[8];
#pragma unroll
  for (int e = 0; e < 8; ++e) dxm[e] = c1v[e];  // dX at t=0 (s=0, piece 0)

  // one layer: 2 own-slice MFMAs pre-barrier (from zb regs), then 3 reads +
  // 6 MFMAs; single depth-4 chain per tile, 2 independent tiles.
  auto layer = [&](const bf16x8(&wf)[2][4], const f32x4(&bv)[2], int rb,
                   f32x4& A0, f32x4& A1) {
    const bf16x8 xo = __builtin_bit_cast(bf16x8, zb);
    f32x4 a0 = MFMA16(wf[0][wv], xo, bv[0]);
    f32x4 a1 = MFMA16(wf[1][wv], xo, bv[1]);
    barrier_lgkm();
    const char* base = lds + rb * 4352;
    const bf16x8 x1 = *(const bf16x8*)(base + off1);
    const bf16x8 x2 = *(const bf16x8*)(base + off2);
    const bf16x8 x3 = *(const bf16x8*)(base + off3);
    a0 = MFMA16(wf[0][ks1], x1, a0);
    a1 = MFMA16(wf[1][ks1], x1, a1);
    a0 = MFMA16(wf[0][ks2], x2, a0);
    a1 = MFMA16(wf[1][ks2], x2, a1);
    a0 = MFMA16(wf[0][ks3], x3, a0);
    a1 = MFMA16(wf[1][ks3], x3, a1);
    A0 = a0; A1 = a1;
  };

  // one MLP eval; exchange buffers: L1 rd sp wr sp^1, L2 rd sp^1 wr sp,
  // L3 rd sp; result (incl. b3) -> kx
  auto run_f = [&](int sp) {
    f32x4 A0, A1;
    float h[8];
    layer(wf1, bv1, sp, A0, A1);
#pragma unroll
    for (int r = 0; r < 4; ++r) {  // ELU(v) = max(v, exp(min(v,0))-1)
      h[r]     = fmaxf(A0[r], __expf(fminf(A0[r], 0.f)) - 1.f);
      h[4 + r] = fmaxf(A1[r], __expf(fminf(A1[r], 0.f)) - 1.f);
    }
    emit(h, sp ^ 1);
    layer(wf2, bv2, sp ^ 1, A0, A1);
#pragma unroll
    for (int r = 0; r < 4; ++r) {
      h[r] = fmaxf(A0[r], 0.f); h[4 + r] = fmaxf(A1[r], 0.f);  // ReLU
    }
    emit(h, sp);
    layer(wf3, bv3, sp, A0, A1);
#pragma unroll
    for (int r = 0; r < 4; ++r) { kx[r] = A0[r]; kx[4 + r] = A1[r]; }
  };

  // ------------- main loop: 64 pieces x 4 unrolled substeps -------------
#pragma unroll 1
  for (int p = 0; p < 64; ++p) {
    const bool pre = p < 63;
    if (pre) coeff_load(p + 1);  // prefetch next piece into regs (vmem queue)

#pragma unroll
    for (int sub = 0; sub < 4; ++sub) {
      const float s0 = 0.25f * (float)sub;  // compile-time

      // ---- stage 1: k1 = f(z)*dX(s0); dx carried in dxm ----
      run_f(0);
      {
        float h[8];
#pragma unroll
        for (int e = 0; e < 8; ++e) {
          kx[e] *= dxm[e]; sacc[e] = kx[e];
          h[e] = fmaf(0.125f, kx[e], zr[e]);
        }
        emit(h, 1);
      }

      // ---- stage 2: k2 at s0+0.125 ----
      run_f(1);
      {
        const float sb = s0 + 0.125f;
        float h[8];
#pragma unroll
        for (int e = 0; e < 8; ++e) {
          dxb[e] = c1v[e] + (c2b[e] + c3b[e] * sb) * sb;
          kx[e] *= dxb[e]; sacc[e] += 2.f * kx[e];
          h[e] = fmaf(0.125f, kx[e], zr[e]);
        }
        emit(h, 0);
      }

      // ---- stage 3: k3 at same s as k2 (dx reused) ----
      run_f(0);
      {
        float h[8];
#pragma unroll
        for (int e = 0; e < 8; ++e) {
          kx[e] *= dxb[e]; sacc[e] += 2.f * kx[e];
          h[e] = fmaf(0.25f, kx[e], zr[e]);
        }
        emit(h, 1);
      }

      // ---- stage 4: k4 at t+dt; dxm set for NEXT stage 1 too ----
      run_f(1);
      if (sub == 3) {
        if (pre) {
#pragma unroll
          for (int e = 0; e < 8; ++e) dxm[e] = cf[e][1];  // next piece, s=0
        } else {
#pragma unroll
          for (int e = 0; e < 8; ++e) dxm[e] = c1v[e] + c2b[e] + c3b[e];  // s=1
        }
      } else {
        const float sc = s0 + 0.25f;
#pragma unroll
        for (int e = 0; e < 8; ++e)
          dxm[e] = c1v[e] + (c2b[e] + c3b[e] * sc) * sc;
      }
      {
        float h[8];
#pragma unroll
        for (int e = 0; e < 8; ++e) {
          const float k4 = kx[e] * dxm[e];
          sacc[e] += k4;
          zr[e] = fmaf(0.25f / 6.f, sacc[e], zr[e]);
          h[e] = zr[e];
        }
        emit(h, 0);  // next step's f-input -> buf0
      }
    }
    if (pre) coeff_adopt();
  }

  // ------------- readout: out = zT @ Wr + br -------------
  __syncthreads();  // all exchange reads done; reuse LDS as fp32 zf[16][132]
  {
    float* zf = (float*)lds;
    *(f32x4*)(zf + l15 * 132 + 32 * wv + 4 * q)      = f32x4{zr[0], zr[1], zr[2], zr[3]};
    *(f32x4*)(zf + l15 * 132 + 32 * wv + 16 + 4 * q) = f32x4{zr[4], zr[5], zr[6], zr[7]};
  }
  __syncthreads();
  if (tid < 160) {
    const int row = tid / 10, o = tid - row * 10;
    const float* zf = (const float*)lds;
    float acc = br[o];
#pragma unroll 4
    for (int ch = 0; ch < 128; ++ch)
      acc = fmaf(zf[row * 132 + ch], Wr[ch * 10 + o], acc);
    out[(size_t)(row0 + row) * 10 + o] = acc;
  }
}

extern "C" void kernel_launch(void* const* d_in, const int* in_sizes, int n_in,
                              void* d_out, int out_size, void* d_ws, size_t ws_size,
                              hipStream_t stream) {
  const float* z0     = (const float*)d_in[0];
  const float* coeffs = (const float*)d_in[1];
  const float* W1 = (const float*)d_in[2]; const float* b1 = (const float*)d_in[3];
  const float* W2 = (const float*)d_in[4]; const float* b2 = (const float*)d_in[5];
  const float* W3 = (const float*)d_in[6]; const float* b3 = (const float*)d_in[7];
  const float* Wr = (const float*)d_in[8]; const float* br = (const float*)d_in[9];
  hipLaunchKernelGGL(cde_fused, dim3(256), dim3(256), 0, stream,
                     z0, coeffs, W1, b1, W2, b2, W3, b3, Wr, br, (float*)d_out);
}